// Round 3
// baseline (766.382 us; speedup 1.0000x reference)
//
#include <hip/hip_runtime.h>
#include <stdint.h>

// Problem constants (match reference)
#define KH 8
#define HD 128
#define GD 64
#define UD 128
#define NPB 128    // nodes per block (8 waves x 16)

// Fragment-major weight image sizes (bf16 elements)
#define WG_K  8192    // per-k Wgh image: 4 t * 4 kb * 64 lanes * 8
#define WU_K 16384    // per-k Wuh image: 8 t * 4 kb * 64 lanes * 8
#define BUFE 24576    // one LDS buffer: WG_K + WU_K elements (48 KB)

typedef __attribute__((ext_vector_type(8))) short short8;   // 8 x bf16 (MFMA A/B frag)
typedef __attribute__((ext_vector_type(4))) float f32x4;    // MFMA C/D frag

__device__ __forceinline__ unsigned short f2bf(float x) {
    union { float f; unsigned u; } v; v.f = x;
    return (unsigned short)((v.u + 0x7fffu + ((v.u >> 16) & 1u)) >> 16);  // RNE
}

__device__ __forceinline__ short8 pack8(const float4 a, const float4 b) {
    short8 r;
    r[0] = (short)f2bf(a.x); r[1] = (short)f2bf(a.y);
    r[2] = (short)f2bf(a.z); r[3] = (short)f2bf(a.w);
    r[4] = (short)f2bf(b.x); r[5] = (short)f2bf(b.y);
    r[6] = (short)f2bf(b.z); r[7] = (short)f2bf(b.w);
    return r;
}

// ---------------- pre-kernel: bf16-convert weights into FRAGMENT-MAJOR images ----------
// For MFMA 16x16x32 B-operand, lane l=(q<<4)|cc of fragment (t,kb) needs
//   WT[col = t*16+cc][h = kb*32 + q*8 + j], j=0..7   (WT = transposed weight, [out][h])
// Image layout: elem index ((t*4+kb)*64 + l)*8 + j  -> every wave ds_read_b128 is
// uniform-base + lane*16B: conflict-free, pad-free, and matches global_load_lds's
// linear wave-uniform destination exactly.
// ws layout (bf16 elements):
//   [0)              : wgImg [k][WG_K]   from Wgh[k][h][g]
//   [KH*WG_K)        : wuImg [k][WU_K]   from Wuh[k][h][u]
//   [.. + KH*WU_K)   : wgvImg [WG_K]     from Wgv[h][g]
__global__ void prep_weights(const float* __restrict__ Wgv,
                             const float* __restrict__ Wgh,
                             const float* __restrict__ Wuh,
                             unsigned short* __restrict__ ws) {
    const int wgN = KH * WG_K;
    const int wuN = KH * WU_K;
    int idx = blockIdx.x * 256 + threadIdx.x;
    if (idx >= wgN + wuN + WG_K) return;
    float val;
    if (idx < wgN) {
        int k = idx >> 13, r = idx & (WG_K - 1);
        int t = r >> 11, kb = (r >> 9) & 3, l = (r >> 3) & 63, j = r & 7;
        int h = kb * 32 + (l >> 4) * 8 + j, g = t * 16 + (l & 15);
        val = Wgh[((size_t)k * HD + h) * GD + g];
    } else if (idx < wgN + wuN) {
        int r0 = idx - wgN;
        int k = r0 >> 14, r = r0 & (WU_K - 1);
        int t = r >> 11, kb = (r >> 9) & 3, l = (r >> 3) & 63, j = r & 7;
        int h = kb * 32 + (l >> 4) * 8 + j, u = t * 16 + (l & 15);
        val = Wuh[((size_t)k * HD + h) * UD + u];
    } else {
        int r = idx - wgN - wuN;
        int t = r >> 11, kb = (r >> 9) & 3, l = (r >> 3) & 63, j = r & 7;
        int h = kb * 32 + (l >> 4) * 8 + j, g = t * 16 + (l & 15);
        val = Wgv[(size_t)h * GD + g];
    }
    ws[idx] = f2bf(val);
}

// async copy of 1KB chunks global->LDS (linear dest == linear source)
__device__ __forceinline__ void cp_lds(const unsigned short* gs, unsigned short* ld,
                                       int nch, int wave, int lane) {
    for (int i = wave; i < nch; i += 8) {
        __builtin_amdgcn_global_load_lds(
            (const __attribute__((address_space(1))) unsigned int*)(gs + i * 512 + lane * 8),
            (__attribute__((address_space(3))) unsigned int*)(ld + i * 512),
            16, 0, 0);
    }
}

// B-fragment read: uniform base + lane*16B, single ds_read_b128, conflict-free
#define BFRAG(base, t, kb) (*(const short8*)&(base)[(((t) * 4 + (kb)) * 64 + lane) * 8])

// ---------------- main kernel ----------------------------------------------------------
// Per block: 128 nodes, 8 waves, 16-node MFMA strip per wave.
// A-fragments (H rows) register-direct from global (no LDS H tile).
// Weights double-buffered in LDS: stage k+1 at TOP of iteration k, single
// __syncthreads() at BOTTOM -> the vmcnt(0) drain overlaps the whole compute phase.
// ONE barrier per k.  LDS = 2 x 48 KB = 96 KB -> 1 block/CU, 8 waves.
__launch_bounds__(512, 2)
__global__ void ghatt_main(const float* __restrict__ vt, const float* __restrict__ H,
                           const unsigned short* __restrict__ ws,
                           float* __restrict__ out, int N) {
    __shared__ __attribute__((aligned(16))) unsigned short lds_w[2 * BUFE]; // 98304 B

    const int tid  = threadIdx.x;
    const int wave = tid >> 6;
    const int lane = tid & 63;
    const int cc   = lane & 15;   // MFMA col / A-row index
    const int q    = lane >> 4;   // quad
    const int nodebase = blockIdx.x * NPB;
    const int anode = nodebase + wave * 16 + cc;   // this lane's A-fragment row
    const bool valid = anode < N;

    const unsigned short* wgImg  = ws;
    const unsigned short* wuImg  = ws + (size_t)KH * WG_K;
    const unsigned short* wgvImg = wuImg + (size_t)KH * WU_K;

    const float4 z4 = make_float4(0.f, 0.f, 0.f, 0.f);
    float4 hreg[8];   // prefetch regs: this lane's 32 floats of H in fragment order

    // ---- prologue: H(0) first (HBM, longest latency), vt frag, wgv->buf1, w[0]->buf0 --
#pragma unroll
    for (int kb = 0; kb < 4; kb++)
#pragma unroll
        for (int j = 0; j < 2; j++)
            hreg[2 * kb + j] = valid ? ((const float4*)H)[(size_t)anode * 32 + kb * 8 + q * 2 + j] : z4;
    float4 vreg[8];
#pragma unroll
    for (int kb = 0; kb < 4; kb++)
#pragma unroll
        for (int j = 0; j < 2; j++)
            vreg[2 * kb + j] = valid ? ((const float4*)vt)[(size_t)anode * 32 + kb * 8 + q * 2 + j] : z4;
    cp_lds(wgvImg, lds_w + BUFE, 16, wave, lane);   // buf1.wg <- WgvT image (phase 0 only)
    cp_lds(wgImg,  lds_w,        16, wave, lane);   // buf0.wg <- Wgh[0]
    cp_lds(wuImg,  lds_w + WG_K, 32, wave, lane);   // buf0.wu <- Wuh[0]
    __syncthreads();   // all staging + vreg/hreg loads complete

    // g_key = vt @ Wgv, C-layout: row(node)=4q+r, col(g)=cc+16t — same layout as gq
    f32x4 gkeyv[4];
    {
        const unsigned short* wgb = lds_w + BUFE;
        short8 vf[4];
#pragma unroll
        for (int kb = 0; kb < 4; kb++) vf[kb] = pack8(vreg[2 * kb], vreg[2 * kb + 1]);
#pragma unroll
        for (int t = 0; t < 4; t++) {
            f32x4 acc = {0.f, 0.f, 0.f, 0.f};
#pragma unroll
            for (int kb = 0; kb < 4; kb++)
                acc = __builtin_amdgcn_mfma_f32_16x16x32_bf16(vf[kb], BFRAG(wgb, t, kb), acc, 0, 0, 0);
            gkeyv[t] = acc;
        }
    }
    __syncthreads();   // all waves done reading buf1 (k=0 will restage it for k=1)

    f32x4 Uacc[8];
#pragma unroll
    for (int t = 0; t < 8; t++) { Uacc[t].x = Uacc[t].y = Uacc[t].z = Uacc[t].w = 0.f; }
    float den[4] = {0.f, 0.f, 0.f, 0.f};

    // ---- k loop: ONE barrier per iteration, stage-early / wait-late --------------------
#pragma unroll 2
    for (int k = 0; k < KH; k++) {
        const int cur = k & 1;
        const unsigned short* wgb = lds_w + cur * BUFE;
        const unsigned short* wub = wgb + WG_K;
        unsigned short* nxt = lds_w + (cur ^ 1) * BUFE;

        short8 va[4];   // pack this k's H fragment (frees hreg for the k+1 prefetch)
#pragma unroll
        for (int kb = 0; kb < 4; kb++) va[kb] = pack8(hreg[2 * kb], hreg[2 * kb + 1]);

        if (k < KH - 1) {
            // issue next H fragment first (HBM), then next weight panels (L2).
            // Both drain at this iteration's bottom barrier — a full compute phase away.
#pragma unroll
            for (int kb = 0; kb < 4; kb++)
#pragma unroll
                for (int j = 0; j < 2; j++)
                    hreg[2 * kb + j] = valid
                        ? ((const float4*)H)[((size_t)(k + 1) * N + anode) * 32 + kb * 8 + q * 2 + j] : z4;
            cp_lds(wgImg + (size_t)(k + 1) * WG_K, nxt,        16, wave, lane);
            cp_lds(wuImg + (size_t)(k + 1) * WU_K, nxt + WG_K, 32, wave, lane);
        }

        // g_query = H @ Wgh[k]  (C-layout, matches gkeyv)
        f32x4 gqv[4];
#pragma unroll
        for (int t = 0; t < 4; t++) {
            f32x4 acc = {0.f, 0.f, 0.f, 0.f};
#pragma unroll
            for (int kb = 0; kb < 4; kb++)
                acc = __builtin_amdgcn_mfma_f32_16x16x32_bf16(va[kb], BFRAG(wgb, t, kb), acc, 0, 0, 0);
            gqv[t] = acc;
        }

        // score: per-row dot over g, reduced across the 16 column-lanes of each quad
        float part[4];
#pragma unroll
        for (int r = 0; r < 4; r++)
            part[r] = gqv[0][r] * gkeyv[0][r] + gqv[1][r] * gkeyv[1][r]
                    + gqv[2][r] * gkeyv[2][r] + gqv[3][r] * gkeyv[3][r];
#pragma unroll
        for (int m2 = 1; m2 < 16; m2 <<= 1) {
#pragma unroll
            for (int r = 0; r < 4; r++) part[r] += __shfl_xor(part[r], m2);
        }
        float gg[4];
#pragma unroll
        for (int r = 0; r < 4; r++) {
            float x = part[r];
            x = (x >= 0.f) ? x : 0.01f * x;      // LeakyReLU(0.01)
            gg[r] = __expf(x * 0.125f);          // / sqrt(64)
            den[r] += gg[r];
        }

        // U += g * (H @ Wuh[k]), all 128 u-columns
#pragma unroll
        for (int t = 0; t < 8; t++) {
            f32x4 acc = {0.f, 0.f, 0.f, 0.f};
#pragma unroll
            for (int kb = 0; kb < 4; kb++)
                acc = __builtin_amdgcn_mfma_f32_16x16x32_bf16(va[kb], BFRAG(wub, t, kb), acc, 0, 0, 0);
#pragma unroll
            for (int r = 0; r < 4; r++) Uacc[t][r] += gg[r] * acc[r];
        }

        __syncthreads();   // drains k+1 staging (had full compute to land) + LDS RAW/WAR
    }

    // ---- epilogue: normalize, lrelu, store ---------------------------------------------
    float inv[4];
#pragma unroll
    for (int r = 0; r < 4; r++) inv[r] = 1.f / den[r];
#pragma unroll
    for (int t = 0; t < 8; t++) {
#pragma unroll
        for (int r = 0; r < 4; r++) {
            float u = Uacc[t][r] * inv[r];
            u = (u >= 0.f) ? u : 0.01f * u;
            int node = nodebase + wave * 16 + 4 * q + r;
            if (node < N) out[(size_t)node * UD + t * 16 + cc] = u;
        }
    }
}

extern "C" void kernel_launch(void* const* d_in, const int* in_sizes, int n_in,
                              void* d_out, int out_size, void* d_ws, size_t ws_size,
                              hipStream_t stream) {
    const float* vt  = (const float*)d_in[0];
    const float* H   = (const float*)d_in[1];
    const float* Wgv = (const float*)d_in[2];
    const float* Wgh = (const float*)d_in[3];
    const float* Wuh = (const float*)d_in[4];
    float* out = (float*)d_out;
    unsigned short* wsw = (unsigned short*)d_ws;

    const int N = in_sizes[0] / HD;   // vt is [N,128]

    // weight prep: KH*(WG_K+WU_K) + WG_K = 204800 bf16 elements = 400 KB of d_ws
    const int prepTot = KH * (WG_K + WU_K) + WG_K;
    hipLaunchKernelGGL(prep_weights, dim3((prepTot + 255) / 256), dim3(256), 0, stream,
                       Wgv, Wgh, Wuh, wsw);

    hipLaunchKernelGGL(ghatt_main, dim3((N + NPB - 1) / NPB), dim3(512), 0, stream,
                       vt, H, wsw, out, N);
}